// Round 2
// baseline (1429.095 us; speedup 1.0000x reference)
//
#include <hip/hip_runtime.h>

#define B_   2
#define S_   2048
#define D_   2048
#define H_   16
#define HD_  128
#define WIN_ 256
#define M_   (B_ * S_)  // 4096

typedef float  f32x4  __attribute__((ext_vector_type(4)));
typedef short  s16x8  __attribute__((ext_vector_type(8)));
typedef __bf16 bf16x8 __attribute__((ext_vector_type(8)));

__device__ inline unsigned short f2b(float f) {
  unsigned u = __builtin_bit_cast(unsigned, f);
  u += 0x7fffu + ((u >> 16) & 1u);  // RNE
  return (unsigned short)(u >> 16);
}
__device__ inline float b2f(unsigned short h) {
  unsigned u = ((unsigned)h) << 16;
  return __builtin_bit_cast(float, u);
}

// Hedged MFMA call: gfx950 builtin may take v8bf16 (upstream clang) or v8i16.
template <typename T>
__device__ auto mfma_impl(T a, T b, f32x4 c, int)
    -> decltype(__builtin_amdgcn_mfma_f32_16x16x32_bf16(a, b, c, 0, 0, 0)) {
  return __builtin_amdgcn_mfma_f32_16x16x32_bf16(a, b, c, 0, 0, 0);
}
template <typename T>
__device__ f32x4 mfma_impl(T a, T b, f32x4 c, long) {
  return __builtin_amdgcn_mfma_f32_16x16x32_bf16(
      __builtin_bit_cast(bf16x8, a), __builtin_bit_cast(bf16x8, b), c, 0, 0, 0);
}
__device__ inline f32x4 mfma_bf16(s16x8 a, s16x8 b, f32x4 c) {
  return mfma_impl(a, b, c, 0);
}

// ---------------- split f32 -> bf16 hi + lo ----------------
__global__ __launch_bounds__(256) void k_split(const float* __restrict__ x,
                                               unsigned short* __restrict__ hi,
                                               unsigned short* __restrict__ lo, int n) {
  int i = (blockIdx.x * 256 + threadIdx.x) * 4;
  if (i + 3 < n) {
    float4 v = *(const float4*)(x + i);
    ushort4 h, l;
    h.x = f2b(v.x); l.x = f2b(v.x - b2f(h.x));
    h.y = f2b(v.y); l.y = f2b(v.y - b2f(h.y));
    h.z = f2b(v.z); l.z = f2b(v.z - b2f(h.z));
    h.w = f2b(v.w); l.w = f2b(v.w - b2f(h.w));
    *(ushort4*)(hi + i) = h;
    *(ushort4*)(lo + i) = l;
  }
}

// ---------------- transpose + split: WT[n][k] = W[k][n] ----------------
__global__ __launch_bounds__(256) void k_transpose(const float* __restrict__ W,
                                                   unsigned short* __restrict__ WTh,
                                                   unsigned short* __restrict__ WTl,
                                                   int R, int C) {
  __shared__ float t[32][33];
  int bx = blockIdx.x * 32, by = blockIdx.y * 32;
  int tx = threadIdx.x, ty = threadIdx.y;  // 32 x 8
#pragma unroll
  for (int r = 0; r < 32; r += 8)
    t[ty + r][tx] = W[(size_t)(by + ty + r) * C + bx + tx];
  __syncthreads();
#pragma unroll
  for (int r = 0; r < 32; r += 8) {
    float v = t[tx][ty + r];
    unsigned short h = f2b(v);
    WTh[(size_t)(bx + ty + r) * R + by + tx] = h;
    WTl[(size_t)(bx + ty + r) * R + by + tx] = f2b(v - b2f(h));
  }
}

// ---------------- split-bf16 MFMA GEMM: C = (Ah+Al)[MxK] * (Bh+Bl)[NxK]^T ----------------
// 64x64 tile, 4 waves as 2x2 of 32x32, BK=32, 3 MFMAs per fragment pair (hh, hl, lh).
__global__ __launch_bounds__(256) void k_gemm3(const unsigned short* __restrict__ Ah,
                                               const unsigned short* __restrict__ Al,
                                               const unsigned short* __restrict__ Bh,
                                               const unsigned short* __restrict__ Bl,
                                               float* __restrict__ C,
                                               const float* __restrict__ bias,
                                               int M, int N, int K) {
  __shared__ unsigned short Ash[64][40];  // +8 pad keeps rows 16B aligned (80B stride)
  __shared__ unsigned short Asl[64][40];
  __shared__ unsigned short Bsh[64][40];
  __shared__ unsigned short Bsl[64][40];
  const int tid = threadIdx.x;
  const int m0 = blockIdx.y * 64, n0 = blockIdx.x * 64;
  const int wave = tid >> 6, lane = tid & 63;
  const int wr = (wave >> 1) * 32, wc = (wave & 1) * 32;
  const int quad = lane >> 4, r16 = lane & 15;
  const int ldrow = tid >> 2, ldcol = (tid & 3) * 8;
  const size_t aoff = (size_t)(m0 + ldrow) * K + ldcol;
  const size_t boff = (size_t)(n0 + ldrow) * K + ldcol;
  f32x4 acc[2][2] = {};
  for (int k0 = 0; k0 < K; k0 += 32) {
    *(uint4*)&Ash[ldrow][ldcol] = *(const uint4*)(Ah + aoff + k0);
    *(uint4*)&Asl[ldrow][ldcol] = *(const uint4*)(Al + aoff + k0);
    *(uint4*)&Bsh[ldrow][ldcol] = *(const uint4*)(Bh + boff + k0);
    *(uint4*)&Bsl[ldrow][ldcol] = *(const uint4*)(Bl + boff + k0);
    __syncthreads();
    s16x8 ah[2], al[2], bh[2], bl[2];
#pragma unroll
    for (int i = 0; i < 2; i++) {
      ah[i] = *(const s16x8*)&Ash[wr + i * 16 + r16][quad * 8];
      al[i] = *(const s16x8*)&Asl[wr + i * 16 + r16][quad * 8];
      bh[i] = *(const s16x8*)&Bsh[wc + i * 16 + r16][quad * 8];
      bl[i] = *(const s16x8*)&Bsl[wc + i * 16 + r16][quad * 8];
    }
#pragma unroll
    for (int i = 0; i < 2; i++)
#pragma unroll
      for (int j = 0; j < 2; j++) {
        acc[i][j] = mfma_bf16(ah[i], bh[j], acc[i][j]);
        acc[i][j] = mfma_bf16(ah[i], bl[j], acc[i][j]);
        acc[i][j] = mfma_bf16(al[i], bh[j], acc[i][j]);
      }
    __syncthreads();
  }
#pragma unroll
  for (int i = 0; i < 2; i++)
#pragma unroll
    for (int j = 0; j < 2; j++)
#pragma unroll
      for (int r = 0; r < 4; r++) {
        int row = m0 + wr + i * 16 + quad * 4 + r;
        int col = n0 + wc + j * 16 + r16;
        float v = acc[i][j][r];
        if (bias) v += bias[col];
        C[(size_t)row * N + col] = v;
      }
}

// ---------------- windowed causal attention (fp32), one wave per query ----------------
// scores are UNSCALED (GPT-Neo sqrt(hd) quirk cancels). Emits AO as bf16 hi/lo pair.
__global__ __launch_bounds__(256) void k_attn(const float* __restrict__ Q,
                                              const float* __restrict__ Kf,
                                              const float* __restrict__ Vf,
                                              const int* __restrict__ amask,
                                              unsigned short* __restrict__ AOh,
                                              unsigned short* __restrict__ AOl) {
  __shared__ float sc[4][256];
  const int tid = threadIdx.x;
  const int wave = tid >> 6, lane = tid & 63;
  const int qblk = blockIdx.x & ((S_ / 4) - 1);  // 512 q-blocks per (b,h)
  const int bh = blockIdx.x >> 9;
  const int b = bh >> 4, h = bh & 15;
  const int i = qblk * 4 + wave;
  const int start = (i >= WIN_ - 1) ? (i - (WIN_ - 1)) : 0;
  const int g = lane >> 4, l16 = lane & 15;

  // q fragment: this lane's 8 dims (l16*8 .. +7), in registers
  const float* qrow = Q + ((size_t)(b * S_ + i) * D_) + h * HD_;
  float qf[8];
  {
    float4 q0 = *(const float4*)(qrow + l16 * 8);
    float4 q1 = *(const float4*)(qrow + l16 * 8 + 4);
    qf[0] = q0.x; qf[1] = q0.y; qf[2] = q0.z; qf[3] = q0.w;
    qf[4] = q1.x; qf[5] = q1.y; qf[6] = q1.z; qf[7] = q1.w;
  }
  // phase 1: scores; 4 keys (one per 16-lane group) per iteration
  for (int c = 0; c < 64; c++) {
    int j = start + c * 4 + g;
    const float* krow = Kf + ((size_t)(b * S_ + j) * D_) + h * HD_;
    float4 k0 = *(const float4*)(krow + l16 * 8);
    float4 k1 = *(const float4*)(krow + l16 * 8 + 4);
    float s = qf[0] * k0.x + qf[1] * k0.y + qf[2] * k0.z + qf[3] * k0.w +
              qf[4] * k1.x + qf[5] * k1.y + qf[6] * k1.z + qf[7] * k1.w;
    s += __shfl_xor(s, 1);
    s += __shfl_xor(s, 2);
    s += __shfl_xor(s, 4);
    s += __shfl_xor(s, 8);
    if ((j > i) || (amask[b * S_ + j] == 0)) s = -3.0e38f;
    if (l16 == 0) sc[wave][c * 4 + g] = s;
  }
  __syncthreads();
  // phase 2: exact softmax over the 256 window slots
  float sv[4], p[4];
#pragma unroll
  for (int c = 0; c < 4; c++) sv[c] = sc[wave][c * 64 + lane];
  float mx = fmaxf(fmaxf(sv[0], sv[1]), fmaxf(sv[2], sv[3]));
  for (int off = 32; off > 0; off >>= 1) mx = fmaxf(mx, __shfl_xor(mx, off));
  float l = 0.f;
#pragma unroll
  for (int c = 0; c < 4; c++) { p[c] = __expf(sv[c] - mx); l += p[c]; }
  for (int off = 32; off > 0; off >>= 1) l += __shfl_xor(l, off);
  float inv = 1.0f / l;
  __syncthreads();
#pragma unroll
  for (int c = 0; c < 4; c++) sc[wave][c * 64 + lane] = p[c] * inv;
  __syncthreads();
  // phase 3: PV; lane owns hd = {lane, lane+64}; coalesced V reads
  float a0 = 0.f, a1 = 0.f;
  const float* vbase = Vf + ((size_t)(b * S_ + start) * D_) + h * HD_;
#pragma unroll 4
  for (int jj = 0; jj < 256; jj++) {
    float pp = sc[wave][jj];
    const float* vrow = vbase + (size_t)jj * D_;
    a0 += pp * vrow[lane];
    a1 += pp * vrow[lane + 64];
  }
  unsigned short* ohrow = AOh + ((size_t)(b * S_ + i) * D_) + h * HD_;
  unsigned short* olrow = AOl + ((size_t)(b * S_ + i) * D_) + h * HD_;
  unsigned short h0 = f2b(a0), h1 = f2b(a1);
  ohrow[lane]      = h0;
  ohrow[lane + 64] = h1;
  olrow[lane]      = f2b(a0 - b2f(h0));
  olrow[lane + 64] = f2b(a1 - b2f(h1));
}

extern "C" void kernel_launch(void* const* d_in, const int* in_sizes, int n_in,
                              void* d_out, int out_size, void* d_ws, size_t ws_size,
                              hipStream_t stream) {
  const float* hs    = (const float*)d_in[0];
  const int*   amask = (const int*)d_in[1];
  const float* Wq    = (const float*)d_in[2];
  const float* Wk    = (const float*)d_in[3];
  const float* Wv    = (const float*)d_in[4];
  const float* Wo    = (const float*)d_in[5];
  const float* bo    = (const float*)d_in[6];
  float* out = (float*)d_out;

  // workspace layout (bytes), total 192 MB:
  //   hsHi 16M | hsLo 16M | 8x Wt halves 8M | Qf 32M | Kf 32M | Vf 32M
  // hsHi/hsLo are reused as AOhi/AOlo after the QKV GEMMs (hs dead by then).
  char* p = (char*)d_ws;
  unsigned short* hsHi = (unsigned short*)p;              p += (size_t)16 << 20;
  unsigned short* hsLo = (unsigned short*)p;              p += (size_t)16 << 20;
  unsigned short* WqTh = (unsigned short*)p;              p += (size_t)8 << 20;
  unsigned short* WqTl = (unsigned short*)p;              p += (size_t)8 << 20;
  unsigned short* WkTh = (unsigned short*)p;              p += (size_t)8 << 20;
  unsigned short* WkTl = (unsigned short*)p;              p += (size_t)8 << 20;
  unsigned short* WvTh = (unsigned short*)p;              p += (size_t)8 << 20;
  unsigned short* WvTl = (unsigned short*)p;              p += (size_t)8 << 20;
  unsigned short* WoTh = (unsigned short*)p;              p += (size_t)8 << 20;
  unsigned short* WoTl = (unsigned short*)p;              p += (size_t)8 << 20;
  float* Qf = (float*)p;                                  p += (size_t)32 << 20;
  float* Kf = (float*)p;                                  p += (size_t)32 << 20;
  float* Vf = (float*)p;                                  p += (size_t)32 << 20;

  k_split<<<M_ * D_ / 1024, 256, 0, stream>>>(hs, hsHi, hsLo, M_ * D_);
  dim3 tb(32, 8), tg(D_ / 32, D_ / 32);
  k_transpose<<<tg, tb, 0, stream>>>(Wq, WqTh, WqTl, D_, D_);
  k_transpose<<<tg, tb, 0, stream>>>(Wk, WkTh, WkTl, D_, D_);
  k_transpose<<<tg, tb, 0, stream>>>(Wv, WvTh, WvTl, D_, D_);
  k_transpose<<<tg, tb, 0, stream>>>(Wo, WoTh, WoTl, D_, D_);

  dim3 gg(D_ / 64, M_ / 64);  // (32, 64)
  k_gemm3<<<gg, 256, 0, stream>>>(hsHi, hsLo, WqTh, WqTl, Qf, nullptr, M_, D_, D_);
  k_gemm3<<<gg, 256, 0, stream>>>(hsHi, hsLo, WkTh, WkTl, Kf, nullptr, M_, D_, D_);
  k_gemm3<<<gg, 256, 0, stream>>>(hsHi, hsLo, WvTh, WvTl, Vf, nullptr, M_, D_, D_);

  k_attn<<<B_ * H_ * (S_ / 4), 256, 0, stream>>>(Qf, Kf, Vf, amask, hsHi /*AOh*/, hsLo /*AOl*/);

  k_gemm3<<<gg, 256, 0, stream>>>(hsHi, hsLo, WoTh, WoTl, out, bo, M_, D_, D_);
}

// Round 3
// 748.558 us; speedup vs baseline: 1.9091x; 1.9091x over previous
//
#include <hip/hip_runtime.h>

#define B_   2
#define S_   2048
#define D_   2048
#define H_   16
#define HD_  128
#define WIN_ 256
#define M_   (B_ * S_)  // 4096

typedef float  f32x4  __attribute__((ext_vector_type(4)));
typedef short  s16x8  __attribute__((ext_vector_type(8)));
typedef __bf16 bf16x8 __attribute__((ext_vector_type(8)));
typedef unsigned short ushort_t;

__device__ inline unsigned short f2b(float f) {
  unsigned u = __builtin_bit_cast(unsigned, f);
  u += 0x7fffu + ((u >> 16) & 1u);  // RNE
  return (unsigned short)(u >> 16);
}
__device__ inline float b2f(unsigned short h) {
  unsigned u = ((unsigned)h) << 16;
  return __builtin_bit_cast(float, u);
}

// Hedged MFMA call: gfx950 builtin may take v8bf16 (upstream clang) or v8i16.
template <typename T>
__device__ auto mfma_impl(T a, T b, f32x4 c, int)
    -> decltype(__builtin_amdgcn_mfma_f32_16x16x32_bf16(a, b, c, 0, 0, 0)) {
  return __builtin_amdgcn_mfma_f32_16x16x32_bf16(a, b, c, 0, 0, 0);
}
template <typename T>
__device__ f32x4 mfma_impl(T a, T b, f32x4 c, long) {
  return __builtin_amdgcn_mfma_f32_16x16x32_bf16(
      __builtin_bit_cast(bf16x8, a), __builtin_bit_cast(bf16x8, b), c, 0, 0, 0);
}
__device__ inline f32x4 mfma_bf16(s16x8 a, s16x8 b, f32x4 c) {
  return mfma_impl(a, b, c, 0);
}

// ---------------- split f32 -> bf16 hi + lo ----------------
__global__ __launch_bounds__(256) void k_split(const float* __restrict__ x,
                                               ushort_t* __restrict__ hi,
                                               ushort_t* __restrict__ lo, int n) {
  int i = (blockIdx.x * 256 + threadIdx.x) * 4;
  if (i + 3 < n) {
    float4 v = *(const float4*)(x + i);
    ushort4 h, l;
    h.x = f2b(v.x); l.x = f2b(v.x - b2f(h.x));
    h.y = f2b(v.y); l.y = f2b(v.y - b2f(h.y));
    h.z = f2b(v.z); l.z = f2b(v.z - b2f(h.z));
    h.w = f2b(v.w); l.w = f2b(v.w - b2f(h.w));
    *(ushort4*)(hi + i) = h;
    *(ushort4*)(lo + i) = l;
  }
}

// ---------------- transpose + split: WT[n][k] = W[k][n]; lo optional ----------------
__global__ __launch_bounds__(256) void k_transpose(const float* __restrict__ W,
                                                   ushort_t* __restrict__ WTh,
                                                   ushort_t* __restrict__ WTl,
                                                   int R, int C) {
  __shared__ float t[32][33];
  int bx = blockIdx.x * 32, by = blockIdx.y * 32;
  int tx = threadIdx.x, ty = threadIdx.y;  // 32 x 8
#pragma unroll
  for (int r = 0; r < 32; r += 8)
    t[ty + r][tx] = W[(size_t)(by + ty + r) * C + bx + tx];
  __syncthreads();
#pragma unroll
  for (int r = 0; r < 32; r += 8) {
    float v = t[tx][ty + r];
    unsigned short h = f2b(v);
    WTh[(size_t)(bx + ty + r) * R + by + tx] = h;
    if (WTl) WTl[(size_t)(bx + ty + r) * R + by + tx] = f2b(v - b2f(h));
  }
}

// ---------------- bf16 transpose for V: Vt[b*D + c][s] = Vb[b*S + s][c] ----------------
__global__ __launch_bounds__(256) void k_vtrans(const ushort_t* __restrict__ Vb,
                                                ushort_t* __restrict__ Vt) {
  __shared__ ushort_t t[32][33];
  int bx = blockIdx.x * 32, by = blockIdx.y * 32, b = blockIdx.z;
  int tx = threadIdx.x, ty = threadIdx.y;  // 32 x 8
#pragma unroll
  for (int r = 0; r < 32; r += 8)
    t[ty + r][tx] = Vb[((size_t)(b * S_ + by + ty + r)) * D_ + bx + tx];
  __syncthreads();
#pragma unroll
  for (int r = 0; r < 32; r += 8)
    Vt[((size_t)(b * D_ + bx + ty + r)) * S_ + by + tx] = t[tx][ty + r];
}

// ---------------- MFMA GEMM: C = A[MxK] * Bt[NxK]^T ----------------
// 64x64 tile, 4 waves as 2x2 of 32x32, BK=32.
// SPLIT3: A,B have hi/lo pairs, 3 MFMAs (hh,hl,lh). OUT: 0=bf16, 1=bf16 hi/lo, 2=f32+bias.
template <bool SPLIT3, int OUT>
__global__ __launch_bounds__(256) void k_gemm(const ushort_t* __restrict__ Ah,
                                              const ushort_t* __restrict__ Al,
                                              const ushort_t* __restrict__ Bh,
                                              const ushort_t* __restrict__ Bl,
                                              ushort_t* __restrict__ Co,
                                              ushort_t* __restrict__ Col,
                                              float* __restrict__ Cf,
                                              const float* __restrict__ bias,
                                              int M, int N, int K) {
  constexpr int NB = SPLIT3 ? 2 : 1;
  __shared__ ushort_t Ash[NB][64][40];  // +8 pad keeps rows 16B aligned
  __shared__ ushort_t Bsh[NB][64][40];
  const int tid = threadIdx.x;
  const int m0 = blockIdx.y * 64, n0 = blockIdx.x * 64;
  const int wave = tid >> 6, lane = tid & 63;
  const int wr = (wave >> 1) * 32, wc = (wave & 1) * 32;
  const int quad = lane >> 4, r16 = lane & 15;
  const int ldrow = tid >> 2, ldcol = (tid & 3) * 8;
  const size_t aoff = (size_t)(m0 + ldrow) * K + ldcol;
  const size_t boff = (size_t)(n0 + ldrow) * K + ldcol;
  f32x4 acc[2][2] = {};
  for (int k0 = 0; k0 < K; k0 += 32) {
    *(uint4*)&Ash[0][ldrow][ldcol] = *(const uint4*)(Ah + aoff + k0);
    *(uint4*)&Bsh[0][ldrow][ldcol] = *(const uint4*)(Bh + boff + k0);
    if (SPLIT3) {
      *(uint4*)&Ash[NB - 1][ldrow][ldcol] = *(const uint4*)(Al + aoff + k0);
      *(uint4*)&Bsh[NB - 1][ldrow][ldcol] = *(const uint4*)(Bl + boff + k0);
    }
    __syncthreads();
#pragma unroll
    for (int i = 0; i < 2; i++)
#pragma unroll
      for (int j = 0; j < 2; j++) {
        s16x8 ah = *(const s16x8*)&Ash[0][wr + i * 16 + r16][quad * 8];
        s16x8 bh = *(const s16x8*)&Bsh[0][wc + j * 16 + r16][quad * 8];
        acc[i][j] = mfma_bf16(ah, bh, acc[i][j]);
        if (SPLIT3) {
          s16x8 al = *(const s16x8*)&Ash[NB - 1][wr + i * 16 + r16][quad * 8];
          s16x8 bl = *(const s16x8*)&Bsh[NB - 1][wc + j * 16 + r16][quad * 8];
          acc[i][j] = mfma_bf16(ah, bl, acc[i][j]);
          acc[i][j] = mfma_bf16(al, bh, acc[i][j]);
        }
      }
    __syncthreads();
  }
#pragma unroll
  for (int i = 0; i < 2; i++)
#pragma unroll
    for (int j = 0; j < 2; j++)
#pragma unroll
      for (int r = 0; r < 4; r++) {
        int row = m0 + wr + i * 16 + quad * 4 + r;
        int col = n0 + wc + j * 16 + r16;
        float v = acc[i][j][r];
        if (OUT == 2) {
          Cf[(size_t)row * N + col] = v + bias[col];
        } else if (OUT == 1) {
          unsigned short h = f2b(v);
          Co[(size_t)row * N + col]  = h;
          Col[(size_t)row * N + col] = f2b(v - b2f(h));
        } else {
          Co[(size_t)row * N + col] = f2b(v);
        }
      }
}

// ---------------- MFMA flash attention, 64-query tile per block ----------------
// Scores: split-3 bf16 QK^T (score-critical). P,V: plain bf16. Online softmax.
// grid: (S/64, H, B); 256 threads = 4 waves, wave w owns queries w*16..w*16+15.
__global__ __launch_bounds__(256) void k_fattn(const ushort_t* __restrict__ Qh,
                                               const ushort_t* __restrict__ Ql,
                                               const ushort_t* __restrict__ Kh,
                                               const ushort_t* __restrict__ Kl,
                                               const ushort_t* __restrict__ Vt,
                                               const int* __restrict__ amask,
                                               ushort_t* __restrict__ AO) {
  __shared__ ushort_t Ksh[64][136];   // [key][dim], +8 pad
  __shared__ ushort_t Ksl[64][136];
  __shared__ ushort_t Vs[128][72];    // [hd][key], +8 pad
  __shared__ ushort_t ps[4][16][72];  // per-wave P scratch [q][key]
  __shared__ int ams[320];
  const int tid = threadIdx.x;
  const int wave = tid >> 6, lane = tid & 63;
  const int quad = lane >> 4, l16 = lane & 15;
  const int qt = blockIdx.x, h = blockIdx.y, b = blockIdx.z;
  const int q0 = qt * 64;

  // stage attention_mask for key range [q0-256, q0+64)
  for (int x = tid; x < 320; x += 256) {
    int j = q0 - 256 + x;
    ams[x] = (j >= 0) ? amask[b * S_ + j] : 0;
  }

  // Q fragments (A-layout: m=l16, k=quad*8+j), resident in registers
  const int qrowA = q0 + wave * 16 + l16;
  const ushort_t* qbh = Qh + ((size_t)(b * S_ + qrowA) * D_) + h * HD_;
  const ushort_t* qbl = Ql + ((size_t)(b * S_ + qrowA) * D_) + h * HD_;
  s16x8 qh[4], ql[4];
#pragma unroll
  for (int kk = 0; kk < 4; kk++) {
    qh[kk] = *(const s16x8*)(qbh + kk * 32 + quad * 8);
    ql[kk] = *(const s16x8*)(qbl + kk * 32 + quad * 8);
  }

  f32x4 O[8] = {};
  float m_run[4], l_run[4];
#pragma unroll
  for (int r = 0; r < 4; r++) { m_run[r] = -3.0e38f; l_run[r] = 0.f; }

  const int t0 = (qt < 4) ? (4 - qt) : 0;  // kb = 64*(qt+t-4) >= 0
  for (int t = t0; t < 5; t++) {
    const int kb = q0 - 256 + 64 * t;
    __syncthreads();
    // stage K tile hi/lo: [key][dim]; thread: key=tid>>2, dims (tid&3)*32..+31
    {
      const int key = tid >> 2, dimb = (tid & 3) * 32;
      const ushort_t* kgh = Kh + ((size_t)(b * S_ + kb + key) * D_) + h * HD_ + dimb;
      const ushort_t* kgl = Kl + ((size_t)(b * S_ + kb + key) * D_) + h * HD_ + dimb;
#pragma unroll
      for (int u = 0; u < 4; u++) {
        *(uint4*)&Ksh[key][dimb + u * 8] = *(const uint4*)(kgh + u * 8);
        *(uint4*)&Ksl[key][dimb + u * 8] = *(const uint4*)(kgl + u * 8);
      }
      // stage V tile (pre-transposed): Vs[hd][key]; thread: hd=tid>>1, keys (tid&1)*32..+31
      const int hd = tid >> 1, keyb = (tid & 1) * 32;
      const ushort_t* vg = Vt + ((size_t)(b * D_ + h * HD_ + hd) * S_) + kb + keyb;
#pragma unroll
      for (int u = 0; u < 4; u++)
        *(uint4*)&Vs[hd][keyb + u * 8] = *(const uint4*)(vg + u * 8);
    }
    __syncthreads();

    // QK^T split-3: sacc[nt] = 16q x 16k tile (keys kb+nt*16..+15)
    f32x4 sacc[4] = {};
#pragma unroll
    for (int kk = 0; kk < 4; kk++)
#pragma unroll
      for (int nt = 0; nt < 4; nt++) {
        s16x8 kfh = *(const s16x8*)&Ksh[nt * 16 + l16][kk * 32 + quad * 8];
        s16x8 kfl = *(const s16x8*)&Ksl[nt * 16 + l16][kk * 32 + quad * 8];
        sacc[nt] = mfma_bf16(qh[kk], kfh, sacc[nt]);
        sacc[nt] = mfma_bf16(qh[kk], kfl, sacc[nt]);
        sacc[nt] = mfma_bf16(ql[kk], kfh, sacc[nt]);
      }

    // mask (C-layout: row q = quad*4+r, col key = nt*16+l16)
#pragma unroll
    for (int nt = 0; nt < 4; nt++) {
      const int j = kb + nt * 16 + l16;
      const bool amok = ams[64 * t + nt * 16 + l16] != 0;
#pragma unroll
      for (int r = 0; r < 4; r++) {
        const int iq = q0 + wave * 16 + quad * 4 + r;
        const bool ok = amok && (j <= iq) && (j > iq - WIN_);
        if (!ok) sacc[nt][r] = -3.0e38f;
      }
    }
    // online softmax
    float mt[4];
#pragma unroll
    for (int r = 0; r < 4; r++) {
      mt[r] = fmaxf(fmaxf(sacc[0][r], sacc[1][r]), fmaxf(sacc[2][r], sacc[3][r]));
      mt[r] = fmaxf(mt[r], __shfl_xor(mt[r], 1));
      mt[r] = fmaxf(mt[r], __shfl_xor(mt[r], 2));
      mt[r] = fmaxf(mt[r], __shfl_xor(mt[r], 4));
      mt[r] = fmaxf(mt[r], __shfl_xor(mt[r], 8));
    }
    float alpha[4], lt[4];
#pragma unroll
    for (int r = 0; r < 4; r++) {
      float mnew = fmaxf(m_run[r], mt[r]);
      alpha[r] = __expf(m_run[r] - mnew);
      m_run[r] = mnew;
      lt[r] = 0.f;
#pragma unroll
      for (int nt = 0; nt < 4; nt++) {
        float s = sacc[nt][r];
        float p = (s > -1.0e30f) ? __expf(s - mnew) : 0.f;  // guard fully-masked rows
        sacc[nt][r] = p;
        lt[r] += p;
      }
      lt[r] += __shfl_xor(lt[r], 1);
      lt[r] += __shfl_xor(lt[r], 2);
      lt[r] += __shfl_xor(lt[r], 4);
      lt[r] += __shfl_xor(lt[r], 8);
      l_run[r] = l_run[r] * alpha[r] + lt[r];
    }
#pragma unroll
    for (int o = 0; o < 8; o++)
#pragma unroll
      for (int r = 0; r < 4; r++) O[o][r] *= alpha[r];
    // P -> A-layout via per-wave LDS scratch (bf16)
#pragma unroll
    for (int nt = 0; nt < 4; nt++)
#pragma unroll
      for (int r = 0; r < 4; r++)
        ps[wave][quad * 4 + r][nt * 16 + l16] = f2b(sacc[nt][r]);
    __syncthreads();
    // PV: O[16q x 128hd] += P(16x64) * V(64x128)
#pragma unroll
    for (int kk2 = 0; kk2 < 2; kk2++) {
      s16x8 pf = *(const s16x8*)&ps[wave][l16][kk2 * 32 + quad * 8];
#pragma unroll
      for (int o = 0; o < 8; o++) {
        s16x8 vf = *(const s16x8*)&Vs[o * 16 + l16][kk2 * 32 + quad * 8];
        O[o] = mfma_bf16(pf, vf, O[o]);
      }
    }
  }
  // epilogue: normalize and store AO (bf16)
#pragma unroll
  for (int r = 0; r < 4; r++) l_run[r] = 1.0f / l_run[r];
#pragma unroll
  for (int o = 0; o < 8; o++)
#pragma unroll
    for (int r = 0; r < 4; r++) {
      int row = q0 + wave * 16 + quad * 4 + r;
      AO[((size_t)(b * S_ + row) * D_) + h * HD_ + o * 16 + l16] = f2b(O[o][r] * l_run[r]);
    }
}

extern "C" void kernel_launch(void* const* d_in, const int* in_sizes, int n_in,
                              void* d_out, int out_size, void* d_ws, size_t ws_size,
                              hipStream_t stream) {
  const float* hs    = (const float*)d_in[0];
  const int*   amask = (const int*)d_in[1];
  const float* Wq    = (const float*)d_in[2];
  const float* Wk    = (const float*)d_in[3];
  const float* Wv    = (const float*)d_in[4];
  const float* Wo    = (const float*)d_in[5];
  const float* bo    = (const float*)d_in[6];
  float* out = (float*)d_out;

  // workspace layout (176 MB total); hsHi reused as AO after V-GEMM.
  char* p = (char*)d_ws;
  ushort_t* hsHi = (ushort_t*)p; p += (size_t)16 << 20;
  ushort_t* hsLo = (ushort_t*)p; p += (size_t)16 << 20;
  ushort_t* WqTh = (ushort_t*)p; p += (size_t)8 << 20;
  ushort_t* WqTl = (ushort_t*)p; p += (size_t)8 << 20;
  ushort_t* WkTh = (ushort_t*)p; p += (size_t)8 << 20;
  ushort_t* WkTl = (ushort_t*)p; p += (size_t)8 << 20;
  ushort_t* WvTh = (ushort_t*)p; p += (size_t)8 << 20;
  ushort_t* WoTh = (ushort_t*)p; p += (size_t)8 << 20;
  ushort_t* Qhb  = (ushort_t*)p; p += (size_t)16 << 20;
  ushort_t* Qlb  = (ushort_t*)p; p += (size_t)16 << 20;
  ushort_t* Khb  = (ushort_t*)p; p += (size_t)16 << 20;
  ushort_t* Klb  = (ushort_t*)p; p += (size_t)16 << 20;
  ushort_t* Vb   = (ushort_t*)p; p += (size_t)16 << 20;
  ushort_t* Vt   = (ushort_t*)p; p += (size_t)16 << 20;

  k_split<<<M_ * D_ / 1024, 256, 0, stream>>>(hs, hsHi, hsLo, M_ * D_);
  dim3 tb(32, 8), tg(D_ / 32, D_ / 32);
  k_transpose<<<tg, tb, 0, stream>>>(Wq, WqTh, WqTl, D_, D_);
  k_transpose<<<tg, tb, 0, stream>>>(Wk, WkTh, WkTl, D_, D_);
  k_transpose<<<tg, tb, 0, stream>>>(Wv, WvTh, nullptr, D_, D_);
  k_transpose<<<tg, tb, 0, stream>>>(Wo, WoTh, nullptr, D_, D_);

  dim3 gg(D_ / 64, M_ / 64);  // (32, 64)
  k_gemm<true, 1><<<gg, 256, 0, stream>>>(hsHi, hsLo, WqTh, WqTl, Qhb, Qlb, nullptr, nullptr, M_, D_, D_);
  k_gemm<true, 1><<<gg, 256, 0, stream>>>(hsHi, hsLo, WkTh, WkTl, Khb, Klb, nullptr, nullptr, M_, D_, D_);
  k_gemm<false, 0><<<gg, 256, 0, stream>>>(hsHi, nullptr, WvTh, nullptr, Vb, nullptr, nullptr, nullptr, M_, D_, D_);

  dim3 vg(D_ / 32, S_ / 32, B_);
  k_vtrans<<<vg, tb, 0, stream>>>(Vb, Vt);

  dim3 ag(S_ / 64, H_, B_);  // (32, 16, 2)
  k_fattn<<<ag, 256, 0, stream>>>(Qhb, Qlb, Khb, Klb, Vt, amask, hsHi /*AO*/);

  k_gemm<false, 2><<<gg, 256, 0, stream>>>(hsHi /*AO*/, nullptr, WoTh, nullptr, nullptr, nullptr, out, bo, M_, D_, D_);
}

// Round 4
// 541.532 us; speedup vs baseline: 2.6390x; 1.3823x over previous
//
#include <hip/hip_runtime.h>

#define B_   2
#define S_   2048
#define D_   2048
#define H_   16
#define HD_  128
#define WIN_ 256
#define M_   (B_ * S_)  // 4096

typedef float  f32x4  __attribute__((ext_vector_type(4)));
typedef short  s16x8  __attribute__((ext_vector_type(8)));
typedef __bf16 bf16x8 __attribute__((ext_vector_type(8)));
typedef unsigned short ushort_t;

__device__ inline unsigned short f2b(float f) {
  unsigned u = __builtin_bit_cast(unsigned, f);
  u += 0x7fffu + ((u >> 16) & 1u);  // RNE
  return (unsigned short)(u >> 16);
}
__device__ inline float b2f(unsigned short h) {
  unsigned u = ((unsigned)h) << 16;
  return __builtin_bit_cast(float, u);
}

// Hedged MFMA call: gfx950 builtin may take v8bf16 (upstream clang) or v8i16.
template <typename T>
__device__ auto mfma_impl(T a, T b, f32x4 c, int)
    -> decltype(__builtin_amdgcn_mfma_f32_16x16x32_bf16(a, b, c, 0, 0, 0)) {
  return __builtin_amdgcn_mfma_f32_16x16x32_bf16(a, b, c, 0, 0, 0);
}
template <typename T>
__device__ f32x4 mfma_impl(T a, T b, f32x4 c, long) {
  return __builtin_amdgcn_mfma_f32_16x16x32_bf16(
      __builtin_bit_cast(bf16x8, a), __builtin_bit_cast(bf16x8, b), c, 0, 0, 0);
}
__device__ inline f32x4 mfma_bf16(s16x8 a, s16x8 b, f32x4 c) {
  return mfma_impl(a, b, c, 0);
}

// ---- async global->LDS, 16B/lane. lds base must be wave-uniform; lane i lands at +i*16B.
#if defined(__has_builtin)
#if __has_builtin(__builtin_amdgcn_global_load_lds)
#define HAS_GLL 1
#endif
#endif
#ifndef HAS_GLL
#define HAS_GLL 0
#endif

__device__ inline void gl_lds16(const ushort_t* g, ushort_t* lds_wave_base) {
#if HAS_GLL
  __builtin_amdgcn_global_load_lds(
      (const __attribute__((address_space(1))) unsigned int*)g,
      (__attribute__((address_space(3))) unsigned int*)lds_wave_base, 16, 0, 0);
#else
  const int lane = threadIdx.x & 63;
  *(uint4*)(lds_wave_base + lane * 8) = *(const uint4*)g;
#endif
}

// ---------------- split f32 -> bf16 hi + lo ----------------
__global__ __launch_bounds__(256) void k_split(const float* __restrict__ x,
                                               ushort_t* __restrict__ hi,
                                               ushort_t* __restrict__ lo, int n) {
  int i = (blockIdx.x * 256 + threadIdx.x) * 4;
  if (i + 3 < n) {
    float4 v = *(const float4*)(x + i);
    ushort4 h, l;
    h.x = f2b(v.x); l.x = f2b(v.x - b2f(h.x));
    h.y = f2b(v.y); l.y = f2b(v.y - b2f(h.y));
    h.z = f2b(v.z); l.z = f2b(v.z - b2f(h.z));
    h.w = f2b(v.w); l.w = f2b(v.w - b2f(h.w));
    *(ushort4*)(hi + i) = h;
    *(ushort4*)(lo + i) = l;
  }
}

// ---------------- transpose + split: WT[n][k] = W[k][n]; lo optional ----------------
__global__ __launch_bounds__(256) void k_transpose(const float* __restrict__ W,
                                                   ushort_t* __restrict__ WTh,
                                                   ushort_t* __restrict__ WTl,
                                                   int R, int C) {
  __shared__ float t[32][33];
  int bx = blockIdx.x * 32, by = blockIdx.y * 32;
  int tx = threadIdx.x, ty = threadIdx.y;  // 32 x 8
#pragma unroll
  for (int r = 0; r < 32; r += 8)
    t[ty + r][tx] = W[(size_t)(by + ty + r) * C + bx + tx];
  __syncthreads();
#pragma unroll
  for (int r = 0; r < 32; r += 8) {
    float v = t[tx][ty + r];
    unsigned short h = f2b(v);
    WTh[(size_t)(bx + ty + r) * R + by + tx] = h;
    if (WTl) WTl[(size_t)(bx + ty + r) * R + by + tx] = f2b(v - b2f(h));
  }
}

// ---------------- bf16 transpose for V: Vt[b*D + c][s] = Vb[b*S + s][c] ----------------
__global__ __launch_bounds__(256) void k_vtrans(const ushort_t* __restrict__ Vb,
                                                ushort_t* __restrict__ Vt) {
  __shared__ ushort_t t[32][33];
  int bx = blockIdx.x * 32, by = blockIdx.y * 32, b = blockIdx.z;
  int tx = threadIdx.x, ty = threadIdx.y;  // 32 x 8
#pragma unroll
  for (int r = 0; r < 32; r += 8)
    t[ty + r][tx] = Vb[((size_t)(b * S_ + by + ty + r)) * D_ + bx + tx];
  __syncthreads();
#pragma unroll
  for (int r = 0; r < 32; r += 8)
    Vt[((size_t)(b * D_ + bx + ty + r)) * S_ + by + tx] = t[tx][ty + r];
}

// ---------------- m97-structure MFMA GEMM: C = A[MxK] * Bt[NxK]^T ----------------
// 128x128 tile, BK=32, global_load_lds width-16 staging, 4 waves 2x2, 4x4 acc/wave.
// SPLIT3: A,B have hi/lo pairs, 3 MFMAs (hh,hl,lh). OUT: 0=bf16, 1=bf16 hi/lo, 2=f32+bias.
template <bool SPLIT3, int OUT>
__global__ __launch_bounds__(256) void k_gemm(const ushort_t* __restrict__ Ah,
                                              const ushort_t* __restrict__ Al,
                                              const ushort_t* __restrict__ Bh,
                                              const ushort_t* __restrict__ Bl,
                                              ushort_t* __restrict__ Co,
                                              ushort_t* __restrict__ Col,
                                              float* __restrict__ Cf,
                                              const float* __restrict__ bias,
                                              int M, int N, int K) {
  constexpr int NB = SPLIT3 ? 2 : 1;
  __shared__ ushort_t Ash[NB][128][32];  // unpadded: layout forced by global_load_lds
  __shared__ ushort_t Bsh[NB][128][32];
  const int tid = threadIdx.x;
  const int wave = tid >> 6, lane = tid & 63;
  const int m0 = blockIdx.y * 128, n0 = blockIdx.x * 128;
  const int wr = (wave >> 1) * 64, wc = (wave & 1) * 64;
  const int quad = lane >> 4, l16 = lane & 15;
  // staging: thread -> (row=tid>>2 in 0..63, 16B chunk (tid&3)); two 64-row issues
  const int srow = tid >> 2, scol = (tid & 3) * 8;
  const size_t aoff = (size_t)(m0 + srow) * K + scol;
  const size_t boff = (size_t)(n0 + srow) * K + scol;
  const int wofs = wave * 512;  // ushort offset of this wave's 1KB chunk

  f32x4 acc[4][4] = {};
  for (int k0 = 0; k0 < K; k0 += 32) {
#pragma unroll
    for (int s = 0; s < NB; s++) {
      const ushort_t* Asrc = (SPLIT3 && s) ? (Al + aoff + k0) : (Ah + aoff + k0);
      const ushort_t* Bsrc = (SPLIT3 && s) ? (Bl + boff + k0) : (Bh + boff + k0);
      gl_lds16(Asrc,                 &Ash[s][0][0] + wofs);
      gl_lds16(Asrc + (size_t)64 * K, &Ash[s][64][0] + wofs);
      gl_lds16(Bsrc,                 &Bsh[s][0][0] + wofs);
      gl_lds16(Bsrc + (size_t)64 * K, &Bsh[s][64][0] + wofs);
    }
    __syncthreads();
    s16x8 bf[NB][4];
#pragma unroll
    for (int s = 0; s < NB; s++)
#pragma unroll
      for (int jt = 0; jt < 4; jt++)
        bf[s][jt] = *(const s16x8*)&Bsh[s][wc + jt * 16 + l16][quad * 8];
#pragma unroll
    for (int it = 0; it < 4; it++) {
      s16x8 ah = *(const s16x8*)&Ash[0][wr + it * 16 + l16][quad * 8];
      s16x8 al;
      if (SPLIT3) al = *(const s16x8*)&Ash[NB - 1][wr + it * 16 + l16][quad * 8];
#pragma unroll
      for (int jt = 0; jt < 4; jt++) {
        acc[it][jt] = mfma_bf16(ah, bf[0][jt], acc[it][jt]);
        if (SPLIT3) {
          acc[it][jt] = mfma_bf16(ah, bf[NB - 1][jt], acc[it][jt]);
          acc[it][jt] = mfma_bf16(al, bf[0][jt], acc[it][jt]);
        }
      }
    }
    __syncthreads();
  }
#pragma unroll
  for (int it = 0; it < 4; it++)
#pragma unroll
    for (int jt = 0; jt < 4; jt++)
#pragma unroll
      for (int r = 0; r < 4; r++) {
        int row = m0 + wr + it * 16 + quad * 4 + r;
        int col = n0 + wc + jt * 16 + l16;
        float v = acc[it][jt][r];
        if (OUT == 2) {
          Cf[(size_t)row * N + col] = v + bias[col];
        } else if (OUT == 1) {
          unsigned short h = f2b(v);
          Co[(size_t)row * N + col]  = h;
          Col[(size_t)row * N + col] = f2b(v - b2f(h));
        } else {
          Co[(size_t)row * N + col] = f2b(v);
        }
      }
}

// ---------------- MFMA flash attention, 64-query tile per block ----------------
// Scores: split-3 bf16 QK^T (score-critical). P,V: plain bf16. Online softmax.
// grid: (S/64, H, B); 256 threads = 4 waves, wave w owns queries w*16..w*16+15.
__global__ __launch_bounds__(256) void k_fattn(const ushort_t* __restrict__ Qh,
                                               const ushort_t* __restrict__ Ql,
                                               const ushort_t* __restrict__ Kh,
                                               const ushort_t* __restrict__ Kl,
                                               const ushort_t* __restrict__ Vt,
                                               const int* __restrict__ amask,
                                               ushort_t* __restrict__ AO) {
  __shared__ ushort_t Ksh[64][136];   // [key][dim], +8 pad
  __shared__ ushort_t Ksl[64][136];
  __shared__ ushort_t Vs[128][72];    // [hd][key], +8 pad
  __shared__ ushort_t ps[4][16][72];  // per-wave P scratch [q][key]
  __shared__ int ams[320];
  const int tid = threadIdx.x;
  const int wave = tid >> 6, lane = tid & 63;
  const int quad = lane >> 4, l16 = lane & 15;
  const int qt = blockIdx.x, h = blockIdx.y, b = blockIdx.z;
  const int q0 = qt * 64;

  for (int x = tid; x < 320; x += 256) {
    int j = q0 - 256 + x;
    ams[x] = (j >= 0) ? amask[b * S_ + j] : 0;
  }

  const int qrowA = q0 + wave * 16 + l16;
  const ushort_t* qbh = Qh + ((size_t)(b * S_ + qrowA) * D_) + h * HD_;
  const ushort_t* qbl = Ql + ((size_t)(b * S_ + qrowA) * D_) + h * HD_;
  s16x8 qh[4], ql[4];
#pragma unroll
  for (int kk = 0; kk < 4; kk++) {
    qh[kk] = *(const s16x8*)(qbh + kk * 32 + quad * 8);
    ql[kk] = *(const s16x8*)(qbl + kk * 32 + quad * 8);
  }

  f32x4 O[8] = {};
  float m_run[4], l_run[4];
#pragma unroll
  for (int r = 0; r < 4; r++) { m_run[r] = -3.0e38f; l_run[r] = 0.f; }

  const int t0 = (qt < 4) ? (4 - qt) : 0;
  for (int t = t0; t < 5; t++) {
    const int kb = q0 - 256 + 64 * t;
    __syncthreads();
    {
      const int key = tid >> 2, dimb = (tid & 3) * 32;
      const ushort_t* kgh = Kh + ((size_t)(b * S_ + kb + key) * D_) + h * HD_ + dimb;
      const ushort_t* kgl = Kl + ((size_t)(b * S_ + kb + key) * D_) + h * HD_ + dimb;
#pragma unroll
      for (int u = 0; u < 4; u++) {
        *(uint4*)&Ksh[key][dimb + u * 8] = *(const uint4*)(kgh + u * 8);
        *(uint4*)&Ksl[key][dimb + u * 8] = *(const uint4*)(kgl + u * 8);
      }
      const int hd = tid >> 1, keyb = (tid & 1) * 32;
      const ushort_t* vg = Vt + ((size_t)(b * D_ + h * HD_ + hd) * S_) + kb + keyb;
#pragma unroll
      for (int u = 0; u < 4; u++)
        *(uint4*)&Vs[hd][keyb + u * 8] = *(const uint4*)(vg + u * 8);
    }
    __syncthreads();

    f32x4 sacc[4] = {};
#pragma unroll
    for (int kk = 0; kk < 4; kk++)
#pragma unroll
      for (int nt = 0; nt < 4; nt++) {
        s16x8 kfh = *(const s16x8*)&Ksh[nt * 16 + l16][kk * 32 + quad * 8];
        s16x8 kfl = *(const s16x8*)&Ksl[nt * 16 + l16][kk * 32 + quad * 8];
        sacc[nt] = mfma_bf16(qh[kk], kfh, sacc[nt]);
        sacc[nt] = mfma_bf16(qh[kk], kfl, sacc[nt]);
        sacc[nt] = mfma_bf16(ql[kk], kfh, sacc[nt]);
      }

#pragma unroll
    for (int nt = 0; nt < 4; nt++) {
      const int j = kb + nt * 16 + l16;
      const bool amok = ams[64 * t + nt * 16 + l16] != 0;
#pragma unroll
      for (int r = 0; r < 4; r++) {
        const int iq = q0 + wave * 16 + quad * 4 + r;
        const bool ok = amok && (j <= iq) && (j > iq - WIN_);
        if (!ok) sacc[nt][r] = -3.0e38f;
      }
    }
    float mt[4];
#pragma unroll
    for (int r = 0; r < 4; r++) {
      mt[r] = fmaxf(fmaxf(sacc[0][r], sacc[1][r]), fmaxf(sacc[2][r], sacc[3][r]));
      mt[r] = fmaxf(mt[r], __shfl_xor(mt[r], 1));
      mt[r] = fmaxf(mt[r], __shfl_xor(mt[r], 2));
      mt[r] = fmaxf(mt[r], __shfl_xor(mt[r], 4));
      mt[r] = fmaxf(mt[r], __shfl_xor(mt[r], 8));
    }
    float alpha[4], lt[4];
#pragma unroll
    for (int r = 0; r < 4; r++) {
      float mnew = fmaxf(m_run[r], mt[r]);
      alpha[r] = __expf(m_run[r] - mnew);
      m_run[r] = mnew;
      lt[r] = 0.f;
#pragma unroll
      for (int nt = 0; nt < 4; nt++) {
        float s = sacc[nt][r];
        float p = (s > -1.0e30f) ? __expf(s - mnew) : 0.f;
        sacc[nt][r] = p;
        lt[r] += p;
      }
      lt[r] += __shfl_xor(lt[r], 1);
      lt[r] += __shfl_xor(lt[r], 2);
      lt[r] += __shfl_xor(lt[r], 4);
      lt[r] += __shfl_xor(lt[r], 8);
      l_run[r] = l_run[r] * alpha[r] + lt[r];
    }
#pragma unroll
    for (int o = 0; o < 8; o++)
#pragma unroll
      for (int r = 0; r < 4; r++) O[o][r] *= alpha[r];
#pragma unroll
    for (int nt = 0; nt < 4; nt++)
#pragma unroll
      for (int r = 0; r < 4; r++)
        ps[wave][quad * 4 + r][nt * 16 + l16] = f2b(sacc[nt][r]);
    __syncthreads();
#pragma unroll
    for (int kk2 = 0; kk2 < 2; kk2++) {
      s16x8 pf = *(const s16x8*)&ps[wave][l16][kk2 * 32 + quad * 8];
#pragma unroll
      for (int o = 0; o < 8; o++) {
        s16x8 vf = *(const s16x8*)&Vs[o * 16 + l16][kk2 * 32 + quad * 8];
        O[o] = mfma_bf16(pf, vf, O[o]);
      }
    }
  }
#pragma unroll
  for (int r = 0; r < 4; r++) l_run[r] = 1.0f / l_run[r];
#pragma unroll
  for (int o = 0; o < 8; o++)
#pragma unroll
    for (int r = 0; r < 4; r++) {
      int row = q0 + wave * 16 + quad * 4 + r;
      AO[((size_t)(b * S_ + row) * D_) + h * HD_ + o * 16 + l16] = f2b(O[o][r] * l_run[r]);
    }
}

extern "C" void kernel_launch(void* const* d_in, const int* in_sizes, int n_in,
                              void* d_out, int out_size, void* d_ws, size_t ws_size,
                              hipStream_t stream) {
  const float* hs    = (const float*)d_in[0];
  const int*   amask = (const int*)d_in[1];
  const float* Wq    = (const float*)d_in[2];
  const float* Wk    = (const float*)d_in[3];
  const float* Wv    = (const float*)d_in[4];
  const float* Wo    = (const float*)d_in[5];
  const float* bo    = (const float*)d_in[6];
  float* out = (float*)d_out;

  // workspace layout (176 MB total); hsHi reused as AO after V-GEMM.
  char* p = (char*)d_ws;
  ushort_t* hsHi = (ushort_t*)p; p += (size_t)16 << 20;
  ushort_t* hsLo = (ushort_t*)p; p += (size_t)16 << 20;
  ushort_t* WqTh = (ushort_t*)p; p += (size_t)8 << 20;
  ushort_t* WqTl = (ushort_t*)p; p += (size_t)8 << 20;
  ushort_t* WkTh = (ushort_t*)p; p += (size_t)8 << 20;
  ushort_t* WkTl = (ushort_t*)p; p += (size_t)8 << 20;
  ushort_t* WvTh = (ushort_t*)p; p += (size_t)8 << 20;
  ushort_t* WoTh = (ushort_t*)p; p += (size_t)8 << 20;
  ushort_t* Qhb  = (ushort_t*)p; p += (size_t)16 << 20;
  ushort_t* Qlb  = (ushort_t*)p; p += (size_t)16 << 20;
  ushort_t* Khb  = (ushort_t*)p; p += (size_t)16 << 20;
  ushort_t* Klb  = (ushort_t*)p; p += (size_t)16 << 20;
  ushort_t* Vb   = (ushort_t*)p; p += (size_t)16 << 20;
  ushort_t* Vt   = (ushort_t*)p; p += (size_t)16 << 20;

  k_split<<<M_ * D_ / 1024, 256, 0, stream>>>(hs, hsHi, hsLo, M_ * D_);
  dim3 tb(32, 8), tg(D_ / 32, D_ / 32);
  k_transpose<<<tg, tb, 0, stream>>>(Wq, WqTh, WqTl, D_, D_);
  k_transpose<<<tg, tb, 0, stream>>>(Wk, WkTh, WkTl, D_, D_);
  k_transpose<<<tg, tb, 0, stream>>>(Wv, WvTh, nullptr, D_, D_);
  k_transpose<<<tg, tb, 0, stream>>>(Wo, WoTh, nullptr, D_, D_);

  dim3 gg(D_ / 128, M_ / 128);  // (16, 32)
  k_gemm<true, 1><<<gg, 256, 0, stream>>>(hsHi, hsLo, WqTh, WqTl, Qhb, Qlb, nullptr, nullptr, M_, D_, D_);
  k_gemm<true, 1><<<gg, 256, 0, stream>>>(hsHi, hsLo, WkTh, WkTl, Khb, Klb, nullptr, nullptr, M_, D_, D_);
  k_gemm<false, 0><<<gg, 256, 0, stream>>>(hsHi, nullptr, WvTh, nullptr, Vb, nullptr, nullptr, nullptr, M_, D_, D_);

  dim3 vg(D_ / 32, S_ / 32, B_);
  k_vtrans<<<vg, tb, 0, stream>>>(Vb, Vt);

  dim3 ag(S_ / 64, H_, B_);  // (32, 16, 2)
  k_fattn<<<ag, 256, 0, stream>>>(Qhb, Qlb, Khb, Klb, Vt, amask, hsHi /*AO*/);

  k_gemm<false, 2><<<gg, 256, 0, stream>>>(hsHi /*AO*/, nullptr, WoTh, nullptr, nullptr, nullptr, out, bo, M_, D_, D_);
}